// Round 5
// baseline (121.034 us; speedup 1.0000x reference)
//
#include <hip/hip_runtime.h>
#include <hip/hip_bf16.h>
#include <hip/hip_fp16.h>

#define BB 8
#define NN 512
#define AH 12
#define DIN 768
#define EE 64
#define MM (BB*NN)          // 4096
#define YY (BB*AH)          // 96
#define LEAKY 0.2f

typedef unsigned short u16;
typedef unsigned int u32;
typedef __attribute__((ext_vector_type(8))) short short8;
typedef __attribute__((ext_vector_type(4))) float f32x4;
typedef __attribute__((ext_vector_type(4))) u32 u32x4;
typedef __attribute__((ext_vector_type(4))) u16 u16x4;
typedef __attribute__((ext_vector_type(4))) _Float16 h16x4;

// float -> bf16 RNE
static __device__ __forceinline__ u16 f2bf(float f) {
    u32 u = __builtin_bit_cast(u32, f);
    u32 r = (u + 0x7FFFu + ((u >> 16) & 1u)) >> 16;
    return (u16)r;
}
static __device__ __forceinline__ u32 pk2(float a, float b) {
    return (u32)f2bf(a) | ((u32)f2bf(b) << 16);
}
// HW packed f32->bf16 RNE (lo = a, hi = b) — same bits as f2bf for normals
static __device__ __forceinline__ u32 cvtpk(float a, float b) {
    u32 r;
    asm("v_cvt_pk_bf16_f32 %0, %1, %2" : "=v"(r) : "v"(a), "v"(b));
    return r;
}
static __device__ __forceinline__ float ftanh(float x) {
    x = fminf(fmaxf(x, -15.f), 15.f);
    return 1.f - 2.f / (__expf(2.f * x) + 1.f);
}
static __device__ __forceinline__ float sigm(float z) {
    z = fminf(fmaxf(z, -80.f), 80.f);
    return 1.f / (1.f + __expf(-z));
}
// async global->LDS, 16B per lane
static __device__ __forceinline__ void gl_lds16(const u16* g, u16* l) {
    __builtin_amdgcn_global_load_lds((const __attribute__((address_space(1))) unsigned int*)g,
                                     (__attribute__((address_space(3))) unsigned int*)l,
                                     16, 0, 0);
}

// ---------------------------------------------------------------------------
// Hardware C/D-layout probe (validated rounds 6-14).
// ---------------------------------------------------------------------------
static __device__ __forceinline__ void mfma_probe(int lane, int* prow, int* pcol) {
    int q = lane >> 4, x = lane & 15;
    short8 af, bf;
#pragma unroll
    for (int j = 0; j < 8; j++) {
        int k = q * 8 + j;
        af[j] = (short)f2bf((k < 16) ? (float)(x * 16 + k) : 0.f);
        bf[j] = (short)f2bf((k == x) ? 1.f : 0.f);
    }
    f32x4 d = {};
    d = __builtin_amdgcn_mfma_f32_16x16x32_bf16(af, bf, d, 0, 0, 0);
#pragma unroll
    for (int r = 0; r < 4; r++) {
        int v = (int)(d[r] + 0.5f);
        prow[r] = v >> 4;
        pcol[r] = v & 15;
    }
}

// ---------------------------------------------------------------------------
// Prep: pack_adj + Hw bf16 conversion + LDS-transposed Wt.
// THIS ROUND: featb path removed entirely (gemm now converts A on the fly).
// ---------------------------------------------------------------------------
#define N_W    (AH*DIN*EE)         // 589824
#define PACK_BLOCKS (MM/4)         // 1024
#define HWBV_BLOCKS ((DIN*DIN)/1024) // 576
#define WT_BLOCKS (AH*(DIN/64))    // 144
#define PREP_BLOCKS (PACK_BLOCKS + HWBV_BLOCKS + WT_BLOCKS)  // 1744

__global__ __launch_bounds__(256) void prep_kernel(const int* __restrict__ adj,
                                                   const float* __restrict__ W,
                                                   const float* __restrict__ Hw,
                                                   u32* __restrict__ maskbuf,
                                                   u16* __restrict__ Wt,
                                                   u16* __restrict__ Hwb) {
    int blk = blockIdx.x, t = threadIdx.x;
    if (blk < PACK_BLOCKS) {
        int w = t >> 6, ln = t & 63;
        int row = blk * 4 + w;
        const int* ar = adj + (size_t)row * NN;
#pragma unroll
        for (int it = 0; it < 8; it++) {
            unsigned long long bal = __ballot(ar[it * 64 + ln] != 0);
            if (ln == 0) {
                maskbuf[row * 16 + it * 2]     = (u32)bal;
                maskbuf[row * 16 + it * 2 + 1] = (u32)(bal >> 32);
            }
        }
        return;
    }
    blk -= PACK_BLOCKS;
    if (blk < HWBV_BLOCKS) {
        int i = blk * 1024 + t * 4;
        float4 v = *(const float4*)&Hw[i];
        u16x4 o = { f2bf(v.x), f2bf(v.y), f2bf(v.z), f2bf(v.w) };
        *(u16x4*)&Hwb[i] = o;
        return;
    }
    blk -= HWBV_BLOCKS;
    // ---- Wt transpose: blk in [0, 144) ----
    __shared__ float tile[64][65];
    int a = blk / (DIN / 64), d0 = (blk % (DIN / 64)) * 64;
    int rl = t >> 4, c4 = (t & 15) * 4;
#pragma unroll
    for (int i = 0; i < 4; i++) {
        int dl = i * 16 + rl;
        float4 v = *(const float4*)&W[((size_t)a * DIN + d0 + dl) * EE + c4];
        tile[dl][c4 + 0] = v.x;
        tile[dl][c4 + 1] = v.y;
        tile[dl][c4 + 2] = v.z;
        tile[dl][c4 + 3] = v.w;
    }
    __syncthreads();
#pragma unroll
    for (int i = 0; i < 4; i++) {
        int e = i * 16 + rl;
        u16x4 o = { f2bf(tile[c4 + 0][e]), f2bf(tile[c4 + 1][e]),
                    f2bf(tile[c4 + 2][e]), f2bf(tile[c4 + 3][e]) };
        *(u16x4*)&Wt[(size_t)a * EE * DIN + (size_t)e * DIN + d0 + c4] = o;
    }
}

// ---------------------------------------------------------------------------
// Fused dual GEMM (h + gate): 64 nodes x (64 e | 64 gate cols), 256 thr,
// grid (64, 12). 2-phase dbuf pipeline (verified R1).
// THIS ROUND: A-tile reg-staged directly from f32 feat (float4 loads at the
// pre-swizzled source offsets -> v_cvt_pk_bf16_f32 -> ds_write_b128, same
// linear LDS layout as gl_lds16 produced). BW/BG staging unchanged.
// ---------------------------------------------------------------------------
__global__ __launch_bounds__(256) void gemm_fused_kernel(const float* __restrict__ featf,
                                                         const u16* __restrict__ Wt,
                                                         const u16* __restrict__ Hwb,
                                                         const float* __restrict__ wsrc,
                                                         const float* __restrict__ wdst,
                                                         const float* __restrict__ Hb,
                                                         u16* __restrict__ hT,
                                                         float2* __restrict__ Spair,
                                                         float2* __restrict__ Dpair,
                                                         _Float16* __restrict__ Gbuf) {
    __shared__ alignas(16) char smem[49152];
    u16* As0 = (u16*)smem;                 // [0,      8K)
    u16* BW0 = (u16*)(smem + 8192);        // [8K,    16K)
    u16* BG0 = (u16*)(smem + 16384);       // [16K,   24K)
    u16* As1 = (u16*)(smem + 24576);       // [24K,   32K)
    u16* BW1 = (u16*)(smem + 32768);       // [32K,   40K)
    u16* BG1 = (u16*)(smem + 40960);       // [40K,   48K)
    float (*cs)[68] = (float (*)[68])smem; // epilogue only; aliases buf0 (17408 B)

    int t = threadIdx.x, w = t >> 6, lane = t & 63, q = lane >> 4, x = lane & 15;
    int m0 = blockIdx.x * 64, a = blockIdx.y;

    int wm = w & 1, wn = w >> 1, xr = x & 7;
    int srow = t >> 3;
    int skoff = ((t & 7) ^ (srow & 7)) * 8;
    const float* Afp = featf + (size_t)(m0 + srow) * DIN + skoff;
    const u16* BWgp = Wt + (size_t)a * EE * DIN + srow * DIN + skoff;
    const u16* BGgp = Hwb + (size_t)(a * EE) * DIN + srow * DIN + skoff;
    int wo = w * 512;
    f32x4 aW00 = {}, aW01 = {}, aW10 = {}, aW11 = {};
    f32x4 aG00 = {}, aG01 = {}, aG10 = {}, aG11 = {};
    float4 av0, av1, av2, av3;   // pending A loads (f32)

#define A_LOAD(K_)                                                \
    do {                                                          \
        const float* ap = Afp + (K_);                             \
        av0 = *(const float4*)ap;                                 \
        av1 = *(const float4*)(ap + 4);                           \
        const float* ap2 = ap + 32 * DIN;                         \
        av2 = *(const float4*)ap2;                                \
        av3 = *(const float4*)(ap2 + 4);                          \
    } while (0)

#define A_WRITE(A_)                                                           \
    do {                                                                      \
        u32x4 w0 = { cvtpk(av0.x, av0.y), cvtpk(av0.z, av0.w),                \
                     cvtpk(av1.x, av1.y), cvtpk(av1.z, av1.w) };              \
        u32x4 w1 = { cvtpk(av2.x, av2.y), cvtpk(av2.z, av2.w),                \
                     cvtpk(av3.x, av3.y), cvtpk(av3.z, av3.w) };              \
        *(u32x4*)((A_) + t * 8) = w0;                                         \
        *(u32x4*)((A_) + 2048 + t * 8) = w1;                                  \
    } while (0)

#define STAGE_B(BW_, BG_, K_)                                     \
    do {                                                          \
        gl_lds16(BWgp + (K_), (BW_) + wo);                        \
        gl_lds16(BWgp + 32 * DIN + (K_), (BW_) + wo + 2048);      \
        gl_lds16(BGgp + (K_), (BG_) + wo);                        \
        gl_lds16(BGgp + 32 * DIN + (K_), (BG_) + wo + 2048);      \
    } while (0)

#define COMPUTE(A_, BW_, BG_)                                                       \
    do {                                                                            \
        const u16* ApA  = (A_)  + (wm * 32 + x) * 64;                               \
        const u16* ApBW = (BW_) + (wn * 32 + x) * 64;                               \
        const u16* ApBG = (BG_) + (wn * 32 + x) * 64;                               \
        _Pragma("unroll")                                                           \
        for (int kk = 0; kk < 2; kk++) {                                            \
            int c8 = ((q + kk * 4) ^ xr) * 8;                                       \
            short8 a0 = *(const short8*)(ApA + c8);                                 \
            short8 a1 = *(const short8*)(ApA + 16 * 64 + c8);                       \
            short8 bW0 = *(const short8*)(ApBW + c8);                               \
            short8 bW1 = *(const short8*)(ApBW + 16 * 64 + c8);                     \
            short8 bG0 = *(const short8*)(ApBG + c8);                               \
            short8 bG1 = *(const short8*)(ApBG + 16 * 64 + c8);                     \
            aW00 = __builtin_amdgcn_mfma_f32_16x16x32_bf16(a0, bW0, aW00, 0, 0, 0); \
            aW01 = __builtin_amdgcn_mfma_f32_16x16x32_bf16(a0, bW1, aW01, 0, 0, 0); \
            aW10 = __builtin_amdgcn_mfma_f32_16x16x32_bf16(a1, bW0, aW10, 0, 0, 0); \
            aW11 = __builtin_amdgcn_mfma_f32_16x16x32_bf16(a1, bW1, aW11, 0, 0, 0); \
            aG00 = __builtin_amdgcn_mfma_f32_16x16x32_bf16(a0, bG0, aG00, 0, 0, 0); \
            aG01 = __builtin_amdgcn_mfma_f32_16x16x32_bf16(a0, bG1, aG01, 0, 0, 0); \
            aG10 = __builtin_amdgcn_mfma_f32_16x16x32_bf16(a1, bG0, aG10, 0, 0, 0); \
            aG11 = __builtin_amdgcn_mfma_f32_16x16x32_bf16(a1, bG1, aG11, 0, 0, 0); \
        }                                                                           \
    } while (0)

    // prologue: stage K-step 0 into buf0
    A_LOAD(0);
    STAGE_B(BW0, BG0, 0);
    A_WRITE(As0);
    __syncthreads();
#pragma unroll 1
    for (int k0 = 0; k0 < DIN; k0 += 128) {
        A_LOAD(k0 + 64);
        STAGE_B(BW1, BG1, k0 + 64);
        COMPUTE(As0, BW0, BG0);
        A_WRITE(As1);
        __syncthreads();                          // buf1 complete; buf0 free
        if (k0 + 128 < DIN) {
            A_LOAD(k0 + 128);
            STAGE_B(BW0, BG0, k0 + 128);
        }
        COMPUTE(As1, BW1, BG1);
        if (k0 + 128 < DIN) A_WRITE(As0);
        __syncthreads();                          // buf0 complete; buf1 free
    }
#undef A_LOAD
#undef A_WRITE
#undef STAGE_B
#undef COMPUTE

    int prow[4], pcol[4];
    mfma_probe(lane, prow, pcol);

    // ---- h: C -> LDS, then hT3 + factored exp pairs ----
#pragma unroll
    for (int r = 0; r < 4; r++) {
        cs[wm * 32 + prow[r]][wn * 32 + pcol[r]]           = aW00[r];
        cs[wm * 32 + prow[r]][wn * 32 + 16 + pcol[r]]      = aW01[r];
        cs[wm * 32 + 16 + prow[r]][wn * 32 + pcol[r]]      = aW10[r];
        cs[wm * 32 + 16 + prow[r]][wn * 32 + 16 + pcol[r]] = aW11[r];
    }
    __syncthreads();

    int b = m0 >> 9;
    int y = b * AH + a;
    int nbase = m0 & 511;
    {
        int kcb = nbase >> 3;
#pragma unroll
        for (int i = 0; i < 2; i++) {
            int idx = i * 256 + t;
            int kcl = idx >> 6, e = idx & 63;
            int r0 = kcl * 8;
            u32x4 wv = { pk2(cs[r0 + 0][e], cs[r0 + 1][e]),
                         pk2(cs[r0 + 2][e], cs[r0 + 3][e]),
                         pk2(cs[r0 + 4][e], cs[r0 + 5][e]),
                         pk2(cs[r0 + 6][e], cs[r0 + 7][e]) };
            *(u32x4*)&hT[((((size_t)y << 6) + kcb + kcl) << 6 | e) * 8] = wv;
        }
    }
    {
        int r = t >> 2, cg = t & 3;
        float s = 0.f, d = 0.f;
#pragma unroll
        for (int i = 0; i < 16; i++) {
            int e2 = cg * 16 + i;
            float th = ftanh(cs[r][e2]);
            s += th * wsrc[a * EE + e2];
            d += th * wdst[a * EE + e2];
        }
        s += __shfl_xor(s, 1); s += __shfl_xor(s, 2);
        d += __shfl_xor(d, 1); d += __shfl_xor(d, 2);
        if (cg == 0) {
            s = fminf(fmaxf(s, -40.f), 40.f);
            d = fminf(fmaxf(d, -40.f), 40.f);
            Spair[y * NN + nbase + r] = make_float2(__expf(s), __expf(0.2f * s));
            Dpair[y * NN + nbase + r] = make_float2(__expf(d), __expf(0.2f * d));
        }
    }
    __syncthreads();

    // ---- gate: C -> LDS, then sigmoid -> Gbuf (f16) ----
#pragma unroll
    for (int r = 0; r < 4; r++) {
        cs[wm * 32 + prow[r]][wn * 32 + pcol[r]]           = aG00[r];
        cs[wm * 32 + prow[r]][wn * 32 + 16 + pcol[r]]      = aG01[r];
        cs[wm * 32 + 16 + prow[r]][wn * 32 + pcol[r]]      = aG10[r];
        cs[wm * 32 + 16 + prow[r]][wn * 32 + 16 + pcol[r]] = aG11[r];
    }
    __syncthreads();

    {
        int n0 = a * EE;
        float4 hb = *(const float4*)&Hb[n0 + (t & 15) * 4];
#pragma unroll
        for (int p = 0; p < 4; p++) {
            int ml = p * 16 + (t >> 4), c4 = (t & 15) * 4;
            float4 v4 = *(const float4*)&cs[ml][c4];
            size_t idx = (size_t)(m0 + ml) * DIN + n0 + c4;
            h16x4 o = { (_Float16)sigm(v4.x + hb.x),
                        (_Float16)sigm(v4.y + hb.y),
                        (_Float16)sigm(v4.z + hb.z),
                        (_Float16)sigm(v4.w + hb.w) };
            *(h16x4*)&Gbuf[idx] = o;
        }
    }
}

// ---------------------------------------------------------------------------
// Attention: pure PV via MFMA + fused elu/gate-blend epilogue. 256 thr,
// grid (8, 96). hT k-chunks staged in LDS (dbuf, verified R2/R4).
// THIS ROUND: epilogue Gbuf/feat operands prefetched before the k-loop
// (T14 issue-early) — hides the tail's global-load latency under the loop.
// ---------------------------------------------------------------------------
__global__ __launch_bounds__(256) void attn_kernel(const u16* __restrict__ hT,
                                                   const float2* __restrict__ Spair,
                                                   const float2* __restrict__ Dpair,
                                                   const u32* __restrict__ maskbuf,
                                                   const float* __restrict__ bias,
                                                   const _Float16* __restrict__ Gbuf,
                                                   const float* __restrict__ feat,
                                                   float* __restrict__ out) {
    __shared__ alignas(16) float2 sd2[NN];
    __shared__ u32 smask[64][17];
    __shared__ float silv[64];
    __shared__ alignas(16) float cs[64][68];
    __shared__ alignas(16) u16 Hs[2][2048];   // 2 x 4KB hT k-chunk buffers

    int t = threadIdx.x;
    int y = blockIdx.y, bb = y / AH, a = y % AH;
    int i0 = blockIdx.x * 64;
    int w = t >> 6, lane = t & 63, q = lane >> 4, x = lane & 15;

    sd2[t] = Dpair[y * NN + t];
    sd2[t + 256] = Dpair[y * NN + 256 + t];
#pragma unroll
    for (int p = 0; p < 4; p++) {
        int idx = p * 256 + t, r = idx >> 4, c = idx & 15;
        smask[r][c] = maskbuf[((bb << 9) + i0 + r) * 16 + c];
    }

    // T14 prefetch: epilogue operands (consumed after the k-loop)
    float4 f4p[4];
    h16x4 g4p[4];
    size_t ebase[4];
#pragma unroll
    for (int p = 0; p < 4; p++) {
        int nl = p * 16 + (t >> 4), e4 = (t & 15) * 4;
        ebase[p] = ((size_t)(bb << 9) + i0 + nl) * DIN + a * EE + e4;
        g4p[p] = *(const h16x4*)&Gbuf[ebase[p]];
        f4p[p] = *(const float4*)&feat[ebase[p]];
    }

    const u16* hTy = hT + ((size_t)y << 12) * 8;     // y * 64 * 64 * 8
    const u16* gstage = hTy + t * 8;                  // per-thread 16B source
    u16* lstage = &Hs[0][0] + w * 512;                // wave-uniform LDS dest

    // prologue: stage k-chunk 0 into Hs[0] (4KB: 256 thr x 16B)
    gl_lds16(gstage, lstage);
    __syncthreads();

    int rowl = w * 16 + x;
    float2 se = Spair[y * NN + i0 + rowl];
    float es1 = se.x, es2 = se.y;

    u32 anym = 0;
#pragma unroll
    for (int c = 0; c < 16; c++) anym |= smask[rowl][c];
    int uni = (anym == 0);

    f32x4 acc[4] = {};
    float lsum = 0.f;

#pragma unroll 2
    for (int k0 = 0; k0 < NN; k0 += 32) {
        int cur = (k0 >> 5) & 1;
        // prefetch next k-chunk into the other buffer
        if (k0 + 32 < NN)
            gl_lds16(gstage + ((k0 + 32) >> 3) * 512, &Hs[cur ^ 1][0] + w * 512);

        u32 mb = smask[rowl][k0 >> 5] >> (q * 8);
        const float4* sdp = (const float4*)&sd2[k0 + q * 8];
        float pv[8];
#pragma unroll
        for (int jj = 0; jj < 4; jj++) {
            float4 d4 = sdp[jj];
            // exp(leaky(s+d)) = max(exp(s+d), exp(0.2(s+d)))
            float p0 = fmaxf(es1 * d4.x, es2 * d4.y);
            float p1 = fmaxf(es1 * d4.z, es2 * d4.w);
            p0 = ((mb >> (2 * jj)) & 1) ? p0 : 0.f;
            p1 = ((mb >> (2 * jj + 1)) & 1) ? p1 : 0.f;
            p0 = uni ? 1.0f : p0;
            p1 = uni ? 1.0f : p1;
            lsum += p0 + p1;
            pv[2 * jj] = p0;
            pv[2 * jj + 1] = p1;
        }
        short8 af = __builtin_bit_cast(short8, (u32x4){
            cvtpk(pv[0], pv[1]), cvtpk(pv[2], pv[3]),
            cvtpk(pv[4], pv[5]), cvtpk(pv[6], pv[7])});
        const u16* hp = &Hs[cur][0] + (q * 64 + x) * 8;
        short8 b0 = *(const short8*)(hp);
        short8 b1 = *(const short8*)(hp + 128);
        short8 b2 = *(const short8*)(hp + 256);
        short8 b3 = *(const short8*)(hp + 384);
        acc[0] = __builtin_amdgcn_mfma_f32_16x16x32_bf16(af, b0, acc[0], 0, 0, 0);
        acc[1] = __builtin_amdgcn_mfma_f32_16x16x32_bf16(af, b1, acc[1], 0, 0, 0);
        acc[2] = __builtin_amdgcn_mfma_f32_16x16x32_bf16(af, b2, acc[2], 0, 0, 0);
        acc[3] = __builtin_amdgcn_mfma_f32_16x16x32_bf16(af, b3, acc[3], 0, 0, 0);
        __syncthreads();
    }

    lsum += __shfl_xor(lsum, 16);
    lsum += __shfl_xor(lsum, 32);
    if (q == 0) silv[rowl] = 1.f / fmaxf(lsum, 1e-30f);

    int prow[4], pcol[4];
    mfma_probe(lane, prow, pcol);
#pragma unroll
    for (int nt = 0; nt < 4; nt++)
#pragma unroll
        for (int r = 0; r < 4; r++)
            cs[w * 16 + prow[r]][nt * 16 + pcol[r]] = acc[nt][r];
    __syncthreads();

    // ---- epilogue: normalize, +bias, elu, gate blend (prefetched g/f) ----
    float4 b4 = *(const float4*)&bias[(t & 15) * 4];
#pragma unroll
    for (int p = 0; p < 4; p++) {
        int nl = p * 16 + (t >> 4), e4 = (t & 15) * 4;
        float il = silv[nl];
        float4 c4 = *(const float4*)&cs[nl][e4];
        h16x4 g4 = g4p[p];
        float4 f4 = f4p[p];
        float4 o;
        float v, e, g;
        v = c4.x * il + b4.x; e = v > 0.f ? v : __expf(v) - 1.f; g = (float)g4.x; o.x = g * e + (1.f - g) * f4.x;
        v = c4.y * il + b4.y; e = v > 0.f ? v : __expf(v) - 1.f; g = (float)g4.y; o.y = g * e + (1.f - g) * f4.y;
        v = c4.z * il + b4.z; e = v > 0.f ? v : __expf(v) - 1.f; g = (float)g4.z; o.z = g * e + (1.f - g) * f4.z;
        v = c4.w * il + b4.w; e = v > 0.f ? v : __expf(v) - 1.f; g = (float)g4.w; o.w = g * e + (1.f - g) * f4.w;
        *(float4*)&out[ebase[p]] = o;
    }
}

// ---------------------------------------------------------------------------
extern "C" void kernel_launch(void* const* d_in, const int* in_sizes, int n_in,
                              void* d_out, int out_size, void* d_ws, size_t ws_size,
                              hipStream_t stream) {
    const float* feat  = (const float*)d_in[0];
    const int*   adj   = (const int*)  d_in[1];
    const float* W     = (const float*)d_in[2];
    const float* bvec  = (const float*)d_in[3];
    const float* wsrc  = (const float*)d_in[4];
    const float* wdst  = (const float*)d_in[5];
    const float* Hw    = (const float*)d_in[6];
    const float* Hb    = (const float*)d_in[7];
    float* out = (float*)d_out;

    char* ws = (char*)d_ws;
    u16*    Wt      = (u16*)(ws);                       // 1,179,648 B
    u16*    Hwb     = (u16*)(ws + 1179648);             // 1,179,648 B
    u16*    hT      = (u16*)(ws + 2359296);             // 6,291,456 B
    float2* Spair   = (float2*)(ws + 8650752);          //   393,216 B
    float2* Dpair   = (float2*)(ws + 9043968);          //   393,216 B
    u32*    maskbuf = (u32*)(ws + 9437184);             //   262,144 B
    _Float16* Gbuf  = (_Float16*)(ws + 9699328);        // 6,291,456 B

    prep_kernel<<<PREP_BLOCKS, 256, 0, stream>>>(
        adj, W, Hw, maskbuf, Wt, Hwb);
    gemm_fused_kernel<<<dim3(MM / 64, AH), 256, 0, stream>>>(
        feat, Wt, Hwb, wsrc, wdst, Hb, hT, Spair, Dpair, Gbuf);
    attn_kernel<<<dim3(NN / 64, YY), 256, 0, stream>>>(
        hT, Spair, Dpair, maskbuf, bvec, Gbuf, feat, out);
}

// Round 6
// 116.631 us; speedup vs baseline: 1.0378x; 1.0378x over previous
//
#include <hip/hip_runtime.h>
#include <hip/hip_bf16.h>
#include <hip/hip_fp16.h>

#define BB 8
#define NN 512
#define AH 12
#define DIN 768
#define EE 64
#define MM (BB*NN)          // 4096
#define YY (BB*AH)          // 96
#define LEAKY 0.2f

typedef unsigned short u16;
typedef unsigned int u32;
typedef __attribute__((ext_vector_type(8))) short short8;
typedef __attribute__((ext_vector_type(4))) float f32x4;
typedef __attribute__((ext_vector_type(4))) u32 u32x4;
typedef __attribute__((ext_vector_type(4))) u16 u16x4;
typedef __attribute__((ext_vector_type(4))) _Float16 h16x4;

// float -> bf16 RNE
static __device__ __forceinline__ u16 f2bf(float f) {
    u32 u = __builtin_bit_cast(u32, f);
    u32 r = (u + 0x7FFFu + ((u >> 16) & 1u)) >> 16;
    return (u16)r;
}
static __device__ __forceinline__ u32 pk2(float a, float b) {
    return (u32)f2bf(a) | ((u32)f2bf(b) << 16);
}
// HW packed f32->bf16 RNE (lo = a, hi = b)
static __device__ __forceinline__ u32 cvtpk(float a, float b) {
    u32 r;
    asm("v_cvt_pk_bf16_f32 %0, %1, %2" : "=v"(r) : "v"(a), "v"(b));
    return r;
}
static __device__ __forceinline__ float ftanh(float x) {
    x = fminf(fmaxf(x, -15.f), 15.f);
    return 1.f - 2.f / (__expf(2.f * x) + 1.f);
}
static __device__ __forceinline__ float sigm(float z) {
    z = fminf(fmaxf(z, -80.f), 80.f);
    return 1.f / (1.f + __expf(-z));
}
// async global->LDS, 16B per lane
static __device__ __forceinline__ void gl_lds16(const u16* g, u16* l) {
    __builtin_amdgcn_global_load_lds((const __attribute__((address_space(1))) unsigned int*)g,
                                     (__attribute__((address_space(3))) unsigned int*)l,
                                     16, 0, 0);
}

// ---------------------------------------------------------------------------
// Hardware C/D-layout probe (validated rounds 6-14).
// ---------------------------------------------------------------------------
static __device__ __forceinline__ void mfma_probe(int lane, int* prow, int* pcol) {
    int q = lane >> 4, x = lane & 15;
    short8 af, bf;
#pragma unroll
    for (int j = 0; j < 8; j++) {
        int k = q * 8 + j;
        af[j] = (short)f2bf((k < 16) ? (float)(x * 16 + k) : 0.f);
        bf[j] = (short)f2bf((k == x) ? 1.f : 0.f);
    }
    f32x4 d = {};
    d = __builtin_amdgcn_mfma_f32_16x16x32_bf16(af, bf, d, 0, 0, 0);
#pragma unroll
    for (int r = 0; r < 4; r++) {
        int v = (int)(d[r] + 0.5f);
        prow[r] = v >> 4;
        pcol[r] = v & 15;
    }
}

// ---------------------------------------------------------------------------
// Prep: pack_adj + vectorized bf16 conversions + LDS-transposed Wt.
// (R0-verified version, featb restored.)
// ---------------------------------------------------------------------------
#define N_FEAT (MM*DIN)            // 3145728
#define N_W    (AH*DIN*EE)         // 589824
#define PACK_BLOCKS (MM/4)         // 1024
#define FEATV_BLOCKS (N_FEAT/1024) // 3072
#define HWBV_BLOCKS ((DIN*DIN)/1024) // 576
#define WT_BLOCKS (AH*(DIN/64))    // 144
#define PREP_BLOCKS (PACK_BLOCKS + FEATV_BLOCKS + HWBV_BLOCKS + WT_BLOCKS)  // 4816

__global__ __launch_bounds__(256) void prep_kernel(const int* __restrict__ adj,
                                                   const float* __restrict__ feat,
                                                   const float* __restrict__ W,
                                                   const float* __restrict__ Hw,
                                                   u32* __restrict__ maskbuf,
                                                   u16* __restrict__ featb,
                                                   u16* __restrict__ Wt,
                                                   u16* __restrict__ Hwb) {
    int blk = blockIdx.x, t = threadIdx.x;
    if (blk < PACK_BLOCKS) {
        int w = t >> 6, ln = t & 63;
        int row = blk * 4 + w;
        const int* ar = adj + (size_t)row * NN;
#pragma unroll
        for (int it = 0; it < 8; it++) {
            unsigned long long bal = __ballot(ar[it * 64 + ln] != 0);
            if (ln == 0) {
                maskbuf[row * 16 + it * 2]     = (u32)bal;
                maskbuf[row * 16 + it * 2 + 1] = (u32)(bal >> 32);
            }
        }
        return;
    }
    blk -= PACK_BLOCKS;
    if (blk < FEATV_BLOCKS) {
        int i = blk * 1024 + t * 4;
        float4 v = *(const float4*)&feat[i];
        u16x4 o = { f2bf(v.x), f2bf(v.y), f2bf(v.z), f2bf(v.w) };
        *(u16x4*)&featb[i] = o;
        return;
    }
    blk -= FEATV_BLOCKS;
    if (blk < HWBV_BLOCKS) {
        int i = blk * 1024 + t * 4;
        float4 v = *(const float4*)&Hw[i];
        u16x4 o = { f2bf(v.x), f2bf(v.y), f2bf(v.z), f2bf(v.w) };
        *(u16x4*)&Hwb[i] = o;
        return;
    }
    blk -= HWBV_BLOCKS;
    // ---- Wt transpose: blk in [0, 144) ----
    __shared__ float tile[64][65];
    int a = blk / (DIN / 64), d0 = (blk % (DIN / 64)) * 64;
    int rl = t >> 4, c4 = (t & 15) * 4;
#pragma unroll
    for (int i = 0; i < 4; i++) {
        int dl = i * 16 + rl;
        float4 v = *(const float4*)&W[((size_t)a * DIN + d0 + dl) * EE + c4];
        tile[dl][c4 + 0] = v.x;
        tile[dl][c4 + 1] = v.y;
        tile[dl][c4 + 2] = v.z;
        tile[dl][c4 + 3] = v.w;
    }
    __syncthreads();
#pragma unroll
    for (int i = 0; i < 4; i++) {
        int e = i * 16 + rl;
        u16x4 o = { f2bf(tile[c4 + 0][e]), f2bf(tile[c4 + 1][e]),
                    f2bf(tile[c4 + 2][e]), f2bf(tile[c4 + 3][e]) };
        *(u16x4*)&Wt[(size_t)a * EE * DIN + (size_t)e * DIN + d0 + c4] = o;
    }
}

// ---------------------------------------------------------------------------
// Fused dual GEMM (h + gate): 64 nodes x (64 e | 64 gate cols), 256 thr,
// grid (64, 12). 2-phase dbuf pipeline (verified R1, best measured config).
// Gate epilogue stores f16 (halves the Gbuf round-trip — the only change
// vs the 118.26 us kernel).
// ---------------------------------------------------------------------------
__global__ __launch_bounds__(256) void gemm_fused_kernel(const u16* __restrict__ featb,
                                                         const u16* __restrict__ Wt,
                                                         const u16* __restrict__ Hwb,
                                                         const float* __restrict__ wsrc,
                                                         const float* __restrict__ wdst,
                                                         const float* __restrict__ Hb,
                                                         u16* __restrict__ hT,
                                                         float2* __restrict__ Spair,
                                                         float2* __restrict__ Dpair,
                                                         _Float16* __restrict__ Gbuf) {
    __shared__ alignas(16) char smem[49152];
    u16* As0 = (u16*)smem;                 // [0,      8K)
    u16* BW0 = (u16*)(smem + 8192);        // [8K,    16K)
    u16* BG0 = (u16*)(smem + 16384);       // [16K,   24K)
    u16* As1 = (u16*)(smem + 24576);       // [24K,   32K)
    u16* BW1 = (u16*)(smem + 32768);       // [32K,   40K)
    u16* BG1 = (u16*)(smem + 40960);       // [40K,   48K)
    float (*cs)[68] = (float (*)[68])smem; // epilogue only; aliases buf0 (17408 B)

    int t = threadIdx.x, w = t >> 6, lane = t & 63, q = lane >> 4, x = lane & 15;
    int m0 = blockIdx.x * 64, a = blockIdx.y;

    int wm = w & 1, wn = w >> 1, xr = x & 7;
    int srow = t >> 3;
    int skoff = ((t & 7) ^ (srow & 7)) * 8;
    const u16* Agp  = featb + (size_t)m0 * DIN + srow * DIN + skoff;
    const u16* BWgp = Wt + (size_t)a * EE * DIN + srow * DIN + skoff;
    const u16* BGgp = Hwb + (size_t)(a * EE) * DIN + srow * DIN + skoff;
    int wo = w * 512;
    f32x4 aW00 = {}, aW01 = {}, aW10 = {}, aW11 = {};
    f32x4 aG00 = {}, aG01 = {}, aG10 = {}, aG11 = {};

#define STAGE(A_, BW_, BG_, K_)                                   \
    do {                                                          \
        gl_lds16(Agp + (K_), (A_) + wo);                          \
        gl_lds16(Agp + 32 * DIN + (K_), (A_) + wo + 2048);        \
        gl_lds16(BWgp + (K_), (BW_) + wo);                        \
        gl_lds16(BWgp + 32 * DIN + (K_), (BW_) + wo + 2048);      \
        gl_lds16(BGgp + (K_), (BG_) + wo);                        \
        gl_lds16(BGgp + 32 * DIN + (K_), (BG_) + wo + 2048);      \
    } while (0)

#define COMPUTE(A_, BW_, BG_)                                                       \
    do {                                                                            \
        const u16* ApA  = (A_)  + (wm * 32 + x) * 64;                               \
        const u16* ApBW = (BW_) + (wn * 32 + x) * 64;                               \
        const u16* ApBG = (BG_) + (wn * 32 + x) * 64;                               \
        _Pragma("unroll")                                                           \
        for (int kk = 0; kk < 2; kk++) {                                            \
            int c8 = ((q + kk * 4) ^ xr) * 8;                                       \
            short8 a0 = *(const short8*)(ApA + c8);                                 \
            short8 a1 = *(const short8*)(ApA + 16 * 64 + c8);                       \
            short8 bW0 = *(const short8*)(ApBW + c8);                               \
            short8 bW1 = *(const short8*)(ApBW + 16 * 64 + c8);                     \
            short8 bG0 = *(const short8*)(ApBG + c8);                               \
            short8 bG1 = *(const short8*)(ApBG + 16 * 64 + c8);                     \
            aW00 = __builtin_amdgcn_mfma_f32_16x16x32_bf16(a0, bW0, aW00, 0, 0, 0); \
            aW01 = __builtin_amdgcn_mfma_f32_16x16x32_bf16(a0, bW1, aW01, 0, 0, 0); \
            aW10 = __builtin_amdgcn_mfma_f32_16x16x32_bf16(a1, bW0, aW10, 0, 0, 0); \
            aW11 = __builtin_amdgcn_mfma_f32_16x16x32_bf16(a1, bW1, aW11, 0, 0, 0); \
            aG00 = __builtin_amdgcn_mfma_f32_16x16x32_bf16(a0, bG0, aG00, 0, 0, 0); \
            aG01 = __builtin_amdgcn_mfma_f32_16x16x32_bf16(a0, bG1, aG01, 0, 0, 0); \
            aG10 = __builtin_amdgcn_mfma_f32_16x16x32_bf16(a1, bG0, aG10, 0, 0, 0); \
            aG11 = __builtin_amdgcn_mfma_f32_16x16x32_bf16(a1, bG1, aG11, 0, 0, 0); \
        }                                                                           \
    } while (0)

    STAGE(As0, BW0, BG0, 0);
    __syncthreads();
#pragma unroll 1
    for (int k0 = 0; k0 < DIN; k0 += 128) {
        STAGE(As1, BW1, BG1, k0 + 64);
        COMPUTE(As0, BW0, BG0);
        __syncthreads();
        if (k0 + 128 < DIN) STAGE(As0, BW0, BG0, k0 + 128);
        COMPUTE(As1, BW1, BG1);
        __syncthreads();
    }
#undef STAGE
#undef COMPUTE

    int prow[4], pcol[4];
    mfma_probe(lane, prow, pcol);

    // ---- h: C -> LDS, then hT3 + factored exp pairs ----
#pragma unroll
    for (int r = 0; r < 4; r++) {
        cs[wm * 32 + prow[r]][wn * 32 + pcol[r]]           = aW00[r];
        cs[wm * 32 + prow[r]][wn * 32 + 16 + pcol[r]]      = aW01[r];
        cs[wm * 32 + 16 + prow[r]][wn * 32 + pcol[r]]      = aW10[r];
        cs[wm * 32 + 16 + prow[r]][wn * 32 + 16 + pcol[r]] = aW11[r];
    }
    __syncthreads();

    int b = m0 >> 9;
    int y = b * AH + a;
    int nbase = m0 & 511;
    {
        int kcb = nbase >> 3;
#pragma unroll
        for (int i = 0; i < 2; i++) {
            int idx = i * 256 + t;
            int kcl = idx >> 6, e = idx & 63;
            int r0 = kcl * 8;
            u32x4 wv = { pk2(cs[r0 + 0][e], cs[r0 + 1][e]),
                         pk2(cs[r0 + 2][e], cs[r0 + 3][e]),
                         pk2(cs[r0 + 4][e], cs[r0 + 5][e]),
                         pk2(cs[r0 + 6][e], cs[r0 + 7][e]) };
            *(u32x4*)&hT[((((size_t)y << 6) + kcb + kcl) << 6 | e) * 8] = wv;
        }
    }
    {
        int r = t >> 2, cg = t & 3;
        float s = 0.f, d = 0.f;
#pragma unroll
        for (int i = 0; i < 16; i++) {
            int e2 = cg * 16 + i;
            float th = ftanh(cs[r][e2]);
            s += th * wsrc[a * EE + e2];
            d += th * wdst[a * EE + e2];
        }
        s += __shfl_xor(s, 1); s += __shfl_xor(s, 2);
        d += __shfl_xor(d, 1); d += __shfl_xor(d, 2);
        if (cg == 0) {
            s = fminf(fmaxf(s, -40.f), 40.f);
            d = fminf(fmaxf(d, -40.f), 40.f);
            Spair[y * NN + nbase + r] = make_float2(__expf(s), __expf(0.2f * s));
            Dpair[y * NN + nbase + r] = make_float2(__expf(d), __expf(0.2f * d));
        }
    }
    __syncthreads();

    // ---- gate: C -> LDS, then sigmoid -> Gbuf (f16) ----
#pragma unroll
    for (int r = 0; r < 4; r++) {
        cs[wm * 32 + prow[r]][wn * 32 + pcol[r]]           = aG00[r];
        cs[wm * 32 + prow[r]][wn * 32 + 16 + pcol[r]]      = aG01[r];
        cs[wm * 32 + 16 + prow[r]][wn * 32 + pcol[r]]      = aG10[r];
        cs[wm * 32 + 16 + prow[r]][wn * 32 + 16 + pcol[r]] = aG11[r];
    }
    __syncthreads();

    {
        int n0 = a * EE;
        float4 hb = *(const float4*)&Hb[n0 + (t & 15) * 4];
#pragma unroll
        for (int p = 0; p < 4; p++) {
            int ml = p * 16 + (t >> 4), c4 = (t & 15) * 4;
            float4 v4 = *(const float4*)&cs[ml][c4];
            size_t idx = (size_t)(m0 + ml) * DIN + n0 + c4;
            h16x4 o = { (_Float16)sigm(v4.x + hb.x),
                        (_Float16)sigm(v4.y + hb.y),
                        (_Float16)sigm(v4.z + hb.z),
                        (_Float16)sigm(v4.w + hb.w) };
            *(h16x4*)&Gbuf[idx] = o;
        }
    }
}

// ---------------------------------------------------------------------------
// Attention: pure PV via MFMA (factored exp, on-the-fly row sum, coalesced
// direct-global hT B-loads — best measured config) + fused elu/gate-blend
// epilogue reading f16 Gbuf. 256 thr, grid (8, 96).
// ---------------------------------------------------------------------------
__global__ __launch_bounds__(256) void attn_kernel(const u16* __restrict__ hT,
                                                   const float2* __restrict__ Spair,
                                                   const float2* __restrict__ Dpair,
                                                   const u32* __restrict__ maskbuf,
                                                   const float* __restrict__ bias,
                                                   const _Float16* __restrict__ Gbuf,
                                                   const float* __restrict__ feat,
                                                   float* __restrict__ out) {
    __shared__ alignas(16) float2 sd2[NN];
    __shared__ u32 smask[64][17];
    __shared__ float silv[64];
    __shared__ alignas(16) float cs[64][68];

    int t = threadIdx.x;
    int y = blockIdx.y, bb = y / AH, a = y % AH;
    int i0 = blockIdx.x * 64;
    int w = t >> 6, lane = t & 63, q = lane >> 4, x = lane & 15;

    sd2[t] = Dpair[y * NN + t];
    sd2[t + 256] = Dpair[y * NN + 256 + t];
#pragma unroll
    for (int p = 0; p < 4; p++) {
        int idx = p * 256 + t, r = idx >> 4, c = idx & 15;
        smask[r][c] = maskbuf[((bb << 9) + i0 + r) * 16 + c];
    }
    __syncthreads();

    int rowl = w * 16 + x;
    float2 se = Spair[y * NN + i0 + rowl];
    float es1 = se.x, es2 = se.y;

    u32 anym = 0;
#pragma unroll
    for (int c = 0; c < 16; c++) anym |= smask[rowl][c];
    int uni = (anym == 0);

    const u16* hTy = hT + ((size_t)y << 12) * 8;     // y * 64 * 64 * 8
    f32x4 acc[4] = {};
    float lsum = 0.f;

#pragma unroll 2
    for (int k0 = 0; k0 < NN; k0 += 32) {
        u32 mb = smask[rowl][k0 >> 5] >> (q * 8);
        const float4* sdp = (const float4*)&sd2[k0 + q * 8];
        float pv[8];
#pragma unroll
        for (int jj = 0; jj < 4; jj++) {
            float4 d4 = sdp[jj];
            // exp(leaky(s+d)) = max(exp(s+d), exp(0.2(s+d)))
            float p0 = fmaxf(es1 * d4.x, es2 * d4.y);
            float p1 = fmaxf(es1 * d4.z, es2 * d4.w);
            p0 = ((mb >> (2 * jj)) & 1) ? p0 : 0.f;
            p1 = ((mb >> (2 * jj + 1)) & 1) ? p1 : 0.f;
            p0 = uni ? 1.0f : p0;
            p1 = uni ? 1.0f : p1;
            lsum += p0 + p1;
            pv[2 * jj] = p0;
            pv[2 * jj + 1] = p1;
        }
        short8 af = __builtin_bit_cast(short8, (u32x4){
            cvtpk(pv[0], pv[1]), cvtpk(pv[2], pv[3]),
            cvtpk(pv[4], pv[5]), cvtpk(pv[6], pv[7])});
        const u16* hp = hTy + ((((k0 >> 3) + q) << 6) + x) * 8;
        short8 b0 = *(const short8*)(hp);
        short8 b1 = *(const short8*)(hp + 16 * 8);
        short8 b2 = *(const short8*)(hp + 32 * 8);
        short8 b3 = *(const short8*)(hp + 48 * 8);
        acc[0] = __builtin_amdgcn_mfma_f32_16x16x32_bf16(af, b0, acc[0], 0, 0, 0);
        acc[1] = __builtin_amdgcn_mfma_f32_16x16x32_bf16(af, b1, acc[1], 0, 0, 0);
        acc[2] = __builtin_amdgcn_mfma_f32_16x16x32_bf16(af, b2, acc[2], 0, 0, 0);
        acc[3] = __builtin_amdgcn_mfma_f32_16x16x32_bf16(af, b3, acc[3], 0, 0, 0);
    }

    lsum += __shfl_xor(lsum, 16);
    lsum += __shfl_xor(lsum, 32);
    if (q == 0) silv[rowl] = 1.f / fmaxf(lsum, 1e-30f);

    int prow[4], pcol[4];
    mfma_probe(lane, prow, pcol);
#pragma unroll
    for (int nt = 0; nt < 4; nt++)
#pragma unroll
        for (int r = 0; r < 4; r++)
            cs[w * 16 + prow[r]][nt * 16 + pcol[r]] = acc[nt][r];
    __syncthreads();

    // ---- epilogue: normalize, +bias, elu, gate blend (f16 Gbuf) ----
    float4 b4 = *(const float4*)&bias[(t & 15) * 4];
#pragma unroll
    for (int p = 0; p < 4; p++) {
        int nl = p * 16 + (t >> 4), e4 = (t & 15) * 4;
        float il = silv[nl];
        float4 c4 = *(const float4*)&cs[nl][e4];
        size_t base = ((size_t)(bb << 9) + i0 + nl) * DIN + a * EE + e4;
        h16x4 g4 = *(const h16x4*)&Gbuf[base];
        float4 f4 = *(const float4*)&feat[base];
        float4 o;
        float v, e, g;
        v = c4.x * il + b4.x; e = v > 0.f ? v : __expf(v) - 1.f; g = (float)g4.x; o.x = g * e + (1.f - g) * f4.x;
        v = c4.y * il + b4.y; e = v > 0.f ? v : __expf(v) - 1.f; g = (float)g4.y; o.y = g * e + (1.f - g) * f4.y;
        v = c4.z * il + b4.z; e = v > 0.f ? v : __expf(v) - 1.f; g = (float)g4.z; o.z = g * e + (1.f - g) * f4.z;
        v = c4.w * il + b4.w; e = v > 0.f ? v : __expf(v) - 1.f; g = (float)g4.w; o.w = g * e + (1.f - g) * f4.w;
        *(float4*)&out[base] = o;
    }
}

// ---------------------------------------------------------------------------
extern "C" void kernel_launch(void* const* d_in, const int* in_sizes, int n_in,
                              void* d_out, int out_size, void* d_ws, size_t ws_size,
                              hipStream_t stream) {
    const float* feat  = (const float*)d_in[0];
    const int*   adj   = (const int*)  d_in[1];
    const float* W     = (const float*)d_in[2];
    const float* bvec  = (const float*)d_in[3];
    const float* wsrc  = (const float*)d_in[4];
    const float* wdst  = (const float*)d_in[5];
    const float* Hw    = (const float*)d_in[6];
    const float* Hb    = (const float*)d_in[7];
    float* out = (float*)d_out;

    char* ws = (char*)d_ws;
    u16*    featb   = (u16*)(ws);                       // 6,291,456 B
    u16*    Wt      = (u16*)(ws + 6291456);             // 1,179,648 B
    u16*    Hwb     = (u16*)(ws + 7471104);             // 1,179,648 B
    u16*    hT      = (u16*)(ws + 8650752);             // 6,291,456 B
    float2* Spair   = (float2*)(ws + 14942208);         //   393,216 B
    float2* Dpair   = (float2*)(ws + 15335424);         //   393,216 B
    u32*    maskbuf = (u32*)(ws + 15728640);            //   262,144 B
    _Float16* Gbuf  = (_Float16*)(ws + 15990784);       // 6,291,456 B (f16)

    prep_kernel<<<PREP_BLOCKS, 256, 0, stream>>>(
        adj, feat, W, Hw, maskbuf, featb, Wt, Hwb);
    gemm_fused_kernel<<<dim3(MM / 64, AH), 256, 0, stream>>>(
        featb, Wt, Hwb, wsrc, wdst, Hb, hT, Spair, Dpair, Gbuf);
    attn_kernel<<<dim3(NN / 64, YY), 256, 0, stream>>>(
        hT, Spair, Dpair, maskbuf, bvec, Gbuf, feat, out);
}